// Round 4
// baseline (105.299 us; speedup 1.0000x reference)
//
#include <hip/hip_runtime.h>
#include <math.h>

#define NS 8192          // sampled points per part (24576/3)
#define NPTS 24576

// chamfer config
#define BXC 64           // threads per chamfer block (1 wave)
#define XPT 16           // x-points per thread
#define XB (NS / (BXC * XPT))   // 8 x-blocks
#define YSPLIT 64
#define YTILE (NS / YSPLIT)     // 128

#define RB 256           // reduce block size
#define RBLOCKS (4 * (NS / RB)) // 128 reduce blocks

typedef __attribute__((ext_vector_type(2))) float f32x2;

// ws float layout:
// [0..3]    accum per combo (combo = part*2 + dir)
// [36]      e_kin
// [37]      (uint) ticket counter for reduce finalize
// [64..]    partial mins: [4 combos][YSPLIT][NS]  (includes +|x|^2)

__device__ inline void build_transform12(const float* __restrict__ rot_quat,
                                         const float* __restrict__ tra,
                                         int p, float* t) {
    float a = rot_quat[p * 4 + 0], b = rot_quat[p * 4 + 1];
    float c = rot_quat[p * 4 + 2], d = rot_quat[p * 4 + 3];
    float inv = rsqrtf(a * a + b * b + c * c + d * d);
    a *= inv; b *= inv; c *= inv; d *= inv;
    t[0]  = 1.f - 2.f * c * c - 2.f * d * d;
    t[1]  = 2.f * b * c - 2.f * a * d;
    t[2]  = 2.f * a * c + 2.f * b * d;
    t[3]  = tra[p * 3 + 0];
    t[4]  = 2.f * b * c + 2.f * a * d;
    t[5]  = 1.f - 2.f * b * b - 2.f * d * d;
    t[6]  = 2.f * c * d - 2.f * a * b;
    t[7]  = tra[p * 3 + 1];
    t[8]  = 2.f * b * d - 2.f * a * c;
    t[9]  = 2.f * a * b + 2.f * c * d;
    t[10] = 1.f - 2.f * b * b - 2.f * c * c;
    t[11] = tra[p * 3 + 2];
}

// Fused prep + pack + chamfer.
// combo = blockIdx.y = p*2 + dir.
//   dir 0: X = transformed cad[p],  Y = cam[p]   (min over cam for each cad pt)
//   dir 1: X = cam[p],              Y = transformed cad[p]
__global__ __launch_bounds__(BXC) void chamfer_kernel(
        const float* __restrict__ cam_pts,
        const float* __restrict__ cad_pts,
        const float* __restrict__ rot_quat,
        const float* __restrict__ tra,
        const float* __restrict__ joint_axes,
        float* __restrict__ ws,
        float* __restrict__ partial,
        float* __restrict__ out) {
    int combo = blockIdx.y;
    int p   = combo >> 1;
    int dir = combo & 1;
    int ys = blockIdx.z;
    int xb = blockIdx.x;
    int t  = threadIdx.x;

    float T[12];
    build_transform12(rot_quat, tra, p, T);

    const float* xsrc = (dir == 0) ? cad_pts : cam_pts;
    const float* ysrc = (dir == 0) ? cam_pts : cad_pts;
    const int pbase = p * NPTS * 3;

    __shared__ float4 sy[YTILE];

    // stage Y tile (transform if it's the cad side)
    int ybase = ys * YTILE;
#pragma unroll
    for (int c = 0; c < YTILE / BXC; ++c) {
        int idx = ybase + c * BXC + t;
        int g = pbase + idx * 9;
        float x = ysrc[g], y = ysrc[g + 1], z = ysrc[g + 2];
        float q0, q1, q2;
        if (dir == 1) {
            q0 = fmaf(T[0], x, fmaf(T[1], y, fmaf(T[2],  z, T[3])));
            q1 = fmaf(T[4], x, fmaf(T[5], y, fmaf(T[6],  z, T[7])));
            q2 = fmaf(T[8], x, fmaf(T[9], y, fmaf(T[10], z, T[11])));
        } else {
            q0 = x; q1 = y; q2 = z;
        }
        sy[c * BXC + t] =
            make_float4(q0, q1, q2, fmaf(q0, q0, fmaf(q1, q1, q2 * q2)));
    }

    // X fragment in registers (transform if it's the cad side)
    int xbase = xb * (BXC * XPT) + t;
    f32x2 m0[XPT / 2], m1[XPT / 2], m2[XPT / 2], s[XPT / 2], dmin[XPT / 2];
#pragma unroll
    for (int g = 0; g < XPT / 2; ++g) {
        float q[2][3];
#pragma unroll
        for (int h = 0; h < 2; ++h) {
            int idx = xbase + (2 * g + h) * BXC;
            int gb = pbase + idx * 9;
            float x = xsrc[gb], y = xsrc[gb + 1], z = xsrc[gb + 2];
            if (dir == 0) {
                q[h][0] = fmaf(T[0], x, fmaf(T[1], y, fmaf(T[2],  z, T[3])));
                q[h][1] = fmaf(T[4], x, fmaf(T[5], y, fmaf(T[6],  z, T[7])));
                q[h][2] = fmaf(T[8], x, fmaf(T[9], y, fmaf(T[10], z, T[11])));
            } else {
                q[h][0] = x; q[h][1] = y; q[h][2] = z;
            }
        }
        m0[g] = (f32x2){-2.f * q[0][0], -2.f * q[1][0]};
        m1[g] = (f32x2){-2.f * q[0][1], -2.f * q[1][1]};
        m2[g] = (f32x2){-2.f * q[0][2], -2.f * q[1][2]};
        s[g]  = (f32x2){
            fmaf(q[0][0], q[0][0], fmaf(q[0][1], q[0][1], q[0][2] * q[0][2])),
            fmaf(q[1][0], q[1][0], fmaf(q[1][1], q[1][1], q[1][2] * q[1][2]))};
        dmin[g] = (f32x2){3.4e38f, 3.4e38f};
    }
    __syncthreads();

    // min_j (|y|^2 - 2 x.y); |x|^2 added in epilogue
#pragma unroll 4
    for (int j = 0; j < YTILE; ++j) {
        float4 y = sy[j];
        f32x2 yw = (f32x2){y.w, y.w};
        f32x2 yx = (f32x2){y.x, y.x};
        f32x2 yy = (f32x2){y.y, y.y};
        f32x2 yz = (f32x2){y.z, y.z};
#pragma unroll
        for (int g = 0; g < XPT / 2; ++g) {
            f32x2 d = __builtin_elementwise_fma(m0[g], yx, yw);
            d = __builtin_elementwise_fma(m1[g], yy, d);
            d = __builtin_elementwise_fma(m2[g], yz, d);
            dmin[g] = __builtin_elementwise_min(dmin[g], d);
        }
    }

    float* prow = partial + (combo * YSPLIT + ys) * NS + xbase;
#pragma unroll
    for (int g = 0; g < XPT / 2; ++g) {
        f32x2 v = dmin[g] + s[g];
        prow[(2 * g) * BXC]     = v.x;
        prow[(2 * g + 1) * BXC] = v.y;
    }

    // prep: one thread of one block emits transforms, e_kin, zeros accums
    if (xb == 0 && combo == 0 && ys == 0 && t == 0) {
        float T0[12], T1[12];
        build_transform12(rot_quat, tra, 0, T0);
        build_transform12(rot_quat, tra, 1, T1);
        for (int k = 0; k < 12; ++k) { out[2 + k] = T0[k]; out[18 + k] = T1[k]; }
        out[14] = 0.f; out[15] = 0.f; out[16] = 0.f; out[17] = 1.f;
        out[30] = 0.f; out[31] = 0.f; out[32] = 0.f; out[33] = 1.f;
        float ss = 0.f;
        for (int r = 0; r < 4; ++r)
            for (int j = 0; j < 2; ++j) {
                float d0 = 0.f, d1 = 0.f;
                for (int k = 0; k < 4; ++k) {
                    float t0k = (r < 3) ? T0[r * 4 + k] : ((k == 3) ? 1.f : 0.f);
                    float t1k = (r < 3) ? T1[r * 4 + k] : ((k == 3) ? 1.f : 0.f);
                    d0 += t0k * joint_axes[j * 4 + k];
                    d1 += t1k * joint_axes[8 + j * 4 + k];
                }
                float df = d0 - d1;
                ss += df * df;
            }
        float ek = 1.f / (1.f + expf(5.f * sqrtf(ss)));
        ws[36] = ek;
        out[1] = ek;
        ws[0] = 0.f; ws[1] = 0.f; ws[2] = 0.f; ws[3] = 0.f;
        ((unsigned*)ws)[37] = 0u;
    }
}

// reduce + finalize fused (last-block ticket)
__global__ void reduce_kernel(const float* __restrict__ partial,
                              const float* __restrict__ pw,
                              float* __restrict__ ws,
                              float* __restrict__ out) {
    int combo = blockIdx.y;
    int x = blockIdx.x * RB + threadIdx.x;
    const float* p = partial + combo * (YSPLIT * NS) + x;
    float m = 3.4e38f;
#pragma unroll 8
    for (int ysi = 0; ysi < YSPLIT; ++ysi) m = fminf(m, p[ysi * NS]);
    float d = sqrtf(fmaxf(m, 0.f));
#pragma unroll
    for (int off = 32; off > 0; off >>= 1) d += __shfl_down(d, off, 64);
    __shared__ float sm[RB / 64];
    int wid = threadIdx.x >> 6;
    if ((threadIdx.x & 63) == 0) sm[wid] = d;
    __syncthreads();
    if (threadIdx.x == 0) {
        float sum = 0.f;
        for (int w = 0; w < RB / 64; ++w) sum += sm[w];
        atomicAdd(&ws[combo], sum);
        __threadfence();
        unsigned old = atomicAdd(&((unsigned*)ws)[37], 1u);
        if (old == RBLOCKS - 1) {
            float a0 = atomicAdd(&ws[0], 0.f);
            float a1 = atomicAdd(&ws[1], 0.f);
            float a2 = atomicAdd(&ws[2], 0.f);
            float a3 = atomicAdd(&ws[3], 0.f);
            float e0 = (a0 + a1) * (1.f / NS);
            float e1 = (a2 + a3) * (1.f / NS);
            out[0] = pw[0] * e0 + pw[1] * e1 + pw[2] * ws[36];
        }
    }
}

extern "C" void kernel_launch(void* const* d_in, const int* in_sizes, int n_in,
                              void* d_out, int out_size, void* d_ws, size_t ws_size,
                              hipStream_t stream) {
    const float* cam = (const float*)d_in[0];
    const float* cad = (const float*)d_in[1];
    const float* pw  = (const float*)d_in[2];
    const float* rq  = (const float*)d_in[3];
    const float* tr  = (const float*)d_in[4];
    const float* ja  = (const float*)d_in[5];
    float* out = (float*)d_out;
    float* ws  = (float*)d_ws;
    float* partial = ws + 64;

    dim3 cg(XB, 4, YSPLIT);
    chamfer_kernel<<<cg, BXC, 0, stream>>>(cam, cad, rq, tr, ja, ws, partial, out);
    reduce_kernel<<<dim3(NS / RB, 4), RB, 0, stream>>>(partial, pw, ws, out);
}